// Round 16
// baseline (547.383 us; speedup 1.0000x reference)
//
#include <hip/hip_runtime.h>
#include <hip/hip_bf16.h>

#define B_ROWS 4096
#define M_ROWS 65536
#define DIM 512
#define TOPK 8
#define CAP 512
#define NR 16               // rescored candidates (top-NR by approx sim)
#define TAU 0.132583f       // 3/sqrt(512): ~88 candidates/query expected
#define FB_N 2048           // fallback merge entries = 256 threads * 8

typedef unsigned short u16;
typedef unsigned int u32;
typedef signed char s8;
typedef unsigned char u8;
typedef int i32x4 __attribute__((ext_vector_type(4)));

__device__ inline void gl_lds16(const void* g, void* l) {
  __builtin_amdgcn_global_load_lds(
      (const __attribute__((address_space(1))) u32*)g,
      (__attribute__((address_space(3))) u32*)l, 16, 0, 0);
}

// ---- normalize rows -> per-row-scaled int8 (one wave per row; fused q+mem) ----
__global__ __launch_bounds__(256) void quant_kernel(const float* __restrict__ mem,
                                                    const float* __restrict__ q,
                                                    s8* __restrict__ mn8,
                                                    s8* __restrict__ qn8,
                                                    float* __restrict__ sb,
                                                    float* __restrict__ sa) {
  int gw = (int)((blockIdx.x * 256 + threadIdx.x) >> 6);
  int lane = threadIdx.x & 63;
  const float* in;
  s8* out;
  float* scale;
  int row;
  if (gw < M_ROWS) {
    in = mem; out = mn8; scale = sb; row = gw;
  } else {
    in = q; out = qn8; scale = sa; row = gw - M_ROWS;
  }
  const float4* r = (const float4*)(in + (size_t)row * DIM);
  float4 v0 = r[lane * 2 + 0];
  float4 v1 = r[lane * 2 + 1];
  float ss = v0.x*v0.x + v0.y*v0.y + v0.z*v0.z + v0.w*v0.w
           + v1.x*v1.x + v1.y*v1.y + v1.z*v1.z + v1.w*v1.w;
#pragma unroll
  for (int off = 32; off > 0; off >>= 1) ss += __shfl_xor(ss, off);
  float inv = 1.0f / fmaxf(sqrtf(ss), 1e-8f);
  float x[8] = {v0.x*inv, v0.y*inv, v0.z*inv, v0.w*inv,
                v1.x*inv, v1.y*inv, v1.z*inv, v1.w*inv};
  float ma = 0.f;
#pragma unroll
  for (int e = 0; e < 8; e++) ma = fmaxf(ma, fabsf(x[e]));
#pragma unroll
  for (int off = 32; off > 0; off >>= 1) ma = fmaxf(ma, __shfl_xor(ma, off));
  float s = fmaxf(ma, 1e-20f) * (1.0f / 127.0f);
  float rs = 1.0f / s;
  u32 lo = 0, hi = 0;
#pragma unroll
  for (int e = 0; e < 4; e++) {
    int qi = __float2int_rn(fminf(fmaxf(x[e] * rs, -127.f), 127.f));
    lo |= ((u32)(u8)(s8)qi) << (8 * e);
  }
#pragma unroll
  for (int e = 0; e < 4; e++) {
    int qi = __float2int_rn(fminf(fmaxf(x[4 + e] * rs, -127.f), 127.f));
    hi |= ((u32)(u8)(s8)qi) << (8 * e);
  }
  uint2 pk; pk.x = lo; pk.y = hi;
  *(uint2*)(out + (size_t)row * DIM + lane * 8) = pk;
  if (lane == 0) scale[row] = s;
}

// ---- int8 MFMA GEMM: 128x128 tile, BK=64 (8 unrolled K-steps), 4 waves.
//      A: ENTIRE K HELD IN REGISTERS (128 VGPR/lane), loaded once at
//      prologue via 32 coalesced global_load_dwordx4 (SSA-tracked, no
//      manual waits). B: LDS ring-2 (16KB), R12-proven vmcnt(0)+barrier
//      pattern + super-row XOR swizzle (0 conflicts). Per step only
//      2 gl_lds + 4 ds_read + 16 MFMA -> serial chain cut ~3x.
//      2 blocks/CU (reg-capped). Epilogue: packed candidates. ----
__global__ __launch_bounds__(256, 2) void gemm_select(const s8* __restrict__ qn,
                                                      const s8* __restrict__ mn,
                                                      const float* __restrict__ sa,
                                                      const float* __restrict__ sb,
                                                      int* __restrict__ count,
                                                      u32* __restrict__ cand) {
  // ring of 2 K-step buffers for B only: [128 rows][64 B] = 8KB each
  __shared__ s8 sB[2][8192];

  // R8-proven mapping: XCD-pair owns a qband of 8 qtiles; 8 consecutive
  // same-XCD blocks share an mtile (8x L2 reuse of mn).
  int bid0 = blockIdx.x;
  int b1 = (bid0 & 7) * 2048 + (bid0 >> 3);
  int qtile = (b1 >> 12) * 8 + (b1 & 7);      // 0..31
  int mtile = (b1 >> 3) & 511;                // 0..511

  int tid = threadIdx.x;
  int lane = tid & 63;
  int w = tid >> 6;
  int wr = w >> 1, wc = w & 1;                // 2 x 2 wave grid; wave tile 64x64
  int rlo = lane & 15;
  int khi16 = (lane >> 4) << 4;               // byte offset of lane's 16B k-slice

  const s8* gB = mn + (size_t)mtile * 128 * DIM;

  // B staging (R12 verbatim): per issue 4KB (256 thr x 16B), dest = tid*16.
  // super-row (128B = 2 rows of 64B) XOR swizzle; source pre-swizzled
  // (inverse permutation) so swizzled READ returns logical data (rule #21).
  int brow_lo = tid >> 3;                     // super-row 0..31 per 4KB issue
  int innb = (tid & 7) << 4;                  // dest inner bytes 0..112
  int inns = innb ^ ((brow_lo & 7) << 4);     // logical inner for this dest slot
  int grow0 = brow_lo * 2 + (inns >> 6);      // logical row 0..63 (issue 0)
  int gcolb = inns & 63;                      // byte col within 64B row

  const s8* gB0 = gB + (size_t)grow0 * DIM + gcolb;
  const s8* gB1 = gB + (size_t)(grow0 + 64) * DIM + gcolb;
  s8* lB0 = &sB[0][w * 1024];
  s8* lB1 = &sB[0][4096 + w * 1024];

  auto stageB = [&](int slot, int kt) {       // 2 vmem ops per thread
    int so = slot * 8192;
    gl_lds16(gB0 + kt * 64, lB0 + so);
    gl_lds16(gB1 + kt * 64, lB1 + so);
  };

  // A: full-K register tile. Lane (rlo, khi16) reads rows wr*64+mi*16+rlo,
  // 16B at kt*64+khi16. Wave touches 16 full 64B lines per load (coalesced;
  // qtile is L2-hot). Plain loads -> compiler-tracked, latency-free hazards.
  i32x4 aA[8][4];
  {
    const s8* gAb = qn + (size_t)(qtile * 128 + wr * 64 + rlo) * DIM + khi16;
#pragma unroll
    for (int kt = 0; kt < 8; kt++)
#pragma unroll
      for (int mi = 0; mi < 4; mi++)
        aA[kt][mi] = *(const i32x4*)(gAb + (size_t)mi * 16 * DIM + kt * 64);
  }

  // B fragment read offsets (loop-invariant phys offsets; slot adds 8192)
  auto physof = [&](int row) {
    int brow = row >> 1;
    return (brow << 7) + ((((row & 1) << 6) + khi16) ^ ((brow & 7) << 4));
  };
  const char* rbB = (const char*)&sB[0][0];
  int offB[4];
#pragma unroll
  for (int i = 0; i < 4; i++) offB[i] = physof(wc * 64 + i * 16 + rlo);

  i32x4 acc[4][4];
#pragma unroll
  for (int i = 0; i < 4; i++)
#pragma unroll
    for (int jj = 0; jj < 4; jj++) {
      i32x4 z = {0, 0, 0, 0};
      acc[i][jj] = z;
    }

  // prologue: stage B K-step 0 into slot 0
  stageB(0, 0);

#pragma unroll
  for (int t = 0; t < 8; t++) {
    // drain outstanding vmem: B(t) landed (issued a full step earlier;
    // at t=0 this also covers the prologue A loads, which we need anyway)
    asm volatile("s_waitcnt vmcnt(0)" ::: "memory");
    __builtin_amdgcn_s_barrier();
    const int cs = t & 1;
    if (t < 7) stageB(cs ^ 1, t + 1); // overwrites slot read at t-1: readers
                                      // retired before this barrier
    i32x4 bF[4];
#pragma unroll
    for (int ni = 0; ni < 4; ni++) bF[ni] = *(const i32x4*)(rbB + cs * 8192 + offB[ni]);
    __builtin_amdgcn_s_setprio(1);
#pragma unroll
    for (int mi = 0; mi < 4; mi++)
#pragma unroll
      for (int ni = 0; ni < 4; ni++)
        acc[mi][ni] = __builtin_amdgcn_mfma_i32_16x16x64_i8(aA[t][mi], bF[ni], acc[mi][ni], 0, 0, 0);
    __builtin_amdgcn_s_setprio(0);
  }

  // epilogue: C row (query) = (lane>>4)*4 + reg, col (mem) = lane&15
  // (C/D layout is dtype-independent on gfx950). v = idot * sa * sb.
  int qbase = qtile * 128 + wr * 64 + (lane >> 4) * 4;
  int mbase = mtile * 128 + wc * 64 + (lane & 15);
#pragma unroll
  for (int mi = 0; mi < 4; mi++) {
    float4 sav = *(const float4*)&sa[qbase + mi * 16];
#pragma unroll
    for (int ni = 0; ni < 4; ni++) {
      float sbv = sb[mbase + ni * 16];
#pragma unroll
      for (int r = 0; r < 4; r++) {
        float v = (float)acc[mi][ni][r] * (sav[r] * sbv);
        if (v > TAU) {
          int qq = qbase + mi * 16 + r;
          u32 pk = (__builtin_bit_cast(u32, v) & 0xFFFF0000u) | (u32)(mbase + ni * 16);
          int pos = atomicAdd(&count[qq], 1);
          if (pos < CAP) cand[(size_t)qq * CAP + pos] = pk;
        }
      }
    }
  }
}

// ---- per-query: top-NR by packed approx sim, fp64 rescore of those rows,
//      exact top-8, gather+mean ----
__global__ __launch_bounds__(256) void topk_kernel(const float* __restrict__ q,
                                                   const float* __restrict__ mem,
                                                   const int* __restrict__ count,
                                                   const u32* __restrict__ cand,
                                                   float* __restrict__ out) {
  __shared__ double s_sims[FB_N];   // fallback merge buffer
  __shared__ int s_cidx[FB_N];
  __shared__ double s_red[4];
  __shared__ int s_redj[4];
  __shared__ u32 s_pk[CAP];
  __shared__ int s_sel[NR];
  __shared__ double s_x[NR];
  __shared__ int s_win[TOPK];

  int b = blockIdx.x;
  int tid = threadIdx.x;
  int lane = tid & 63;
  int w = tid >> 6;

  const float* qrow = q + (size_t)b * DIM;
  const float4* qv = (const float4*)qrow;
  float4 q0 = qv[lane * 2], q1 = qv[lane * 2 + 1];
  double q8[8] = {q0.x, q0.y, q0.z, q0.w, q1.x, q1.y, q1.z, q1.w};
  double qq = 0;
#pragma unroll
  for (int e = 0; e < 8; e++) qq += q8[e] * q8[e];
#pragma unroll
  for (int off = 32; off > 0; off >>= 1) qq += __shfl_xor(qq, off);
  double qnorm = fmax(sqrt(qq), 1e-8);

  int c = count[b];
  if (c >= TOPK && c <= CAP) {
    for (int j = tid; j < c; j += 256) s_pk[j] = cand[(size_t)b * CAP + j];
    __syncthreads();
    int nsel = c < NR ? c : NR;
    if (w == 0) {
      for (int r = 0; r < nsel; r++) {
        int best = -1, bj = -1;
        for (int j = lane; j < c; j += 64) {
          int v = (int)s_pk[j];
          if (v > best) { best = v; bj = j; }
        }
#pragma unroll
        for (int off = 32; off > 0; off >>= 1) {
          int ov = __shfl_down(best, off);
          int oj = __shfl_down(bj, off);
          if (ov > best) { best = ov; bj = oj; }
        }
        bj = __shfl(bj, 0);
        if (lane == 0) { s_sel[r] = (int)(s_pk[bj] & 0xFFFFu); s_pk[bj] = 0; }
      }
    }
    __syncthreads();
    for (int i = w; i < nsel; i += 4) {
      int mi = s_sel[i];
      const float4* mv = (const float4*)(mem + (size_t)mi * DIM);
      float4 m0 = mv[lane * 2], m1 = mv[lane * 2 + 1];
      double m8[8] = {m0.x, m0.y, m0.z, m0.w, m1.x, m1.y, m1.z, m1.w};
      double dot = 0, mm = 0;
#pragma unroll
      for (int e = 0; e < 8; e++) { dot += q8[e] * m8[e]; mm += m8[e] * m8[e]; }
#pragma unroll
      for (int off = 32; off > 0; off >>= 1) {
        dot += __shfl_xor(dot, off);
        mm += __shfl_xor(mm, off);
      }
      if (lane == 0) s_x[i] = dot / (qnorm * fmax(sqrt(mm), 1e-8));
    }
    __syncthreads();
    if (w == 0) {
      double myv = (lane < nsel) ? s_x[lane] : -1e300;
      int myrow = (lane < nsel) ? s_sel[lane] : -1;
      for (int r = 0; r < TOPK; r++) {
        double bv = myv; int bl = lane;
#pragma unroll
        for (int off = 32; off > 0; off >>= 1) {
          double ov = __shfl_down(bv, off);
          int ol = __shfl_down(bl, off);
          if (ov > bv) { bv = ov; bl = ol; }
        }
        bl = __shfl(bl, 0);
        int brow = __shfl(myrow, bl);
        if (lane == 0) s_win[r] = brow;
        if (lane == bl) myv = -1e300;
      }
    }
    __syncthreads();
  } else {
    // fallback (cold, correctness-only): full scan, per-thread top-8, block merge
    double tv[8]; int tix[8];
#pragma unroll
    for (int r = 0; r < 8; r++) { tv[r] = -1e300; tix[r] = -1; }
    for (int row = tid; row < M_ROWS; row += 256) {
      const float4* mv = (const float4*)(mem + (size_t)row * DIM);
      double dot = 0, mm = 0;
      for (int e = 0; e < DIM / 4; e++) {
        float4 m4 = mv[e], qk = qv[e];
        dot += (double)m4.x * qk.x + (double)m4.y * qk.y + (double)m4.z * qk.z + (double)m4.w * qk.w;
        mm  += (double)m4.x * m4.x + (double)m4.y * m4.y + (double)m4.z * m4.z + (double)m4.w * m4.w;
      }
      double sim = dot / (qnorm * fmax(sqrt(mm), 1e-8));
      int am = 0;
#pragma unroll
      for (int r = 1; r < 8; r++) if (tv[r] < tv[am]) am = r;
      if (sim > tv[am]) { tv[am] = sim; tix[am] = row; }
    }
#pragma unroll
    for (int r = 0; r < 8; r++) { s_sims[tid * 8 + r] = tv[r]; s_cidx[tid * 8 + r] = tix[r]; }
    __syncthreads();
    for (int r = 0; r < TOPK; r++) {
      double best = -1e300; int bj = -1;
      for (int j = tid; j < FB_N; j += 256) {
        double v = s_sims[j];
        if (v > best) { best = v; bj = j; }
      }
#pragma unroll
      for (int off = 32; off > 0; off >>= 1) {
        double ov = __shfl_down(best, off);
        int oj = __shfl_down(bj, off);
        if (ov > best) { best = ov; bj = oj; }
      }
      if (lane == 0) { s_red[w] = best; s_redj[w] = bj; }
      __syncthreads();
      if (tid == 0) {
        double bb = s_red[0]; int jj = s_redj[0];
        for (int i = 1; i < 4; i++) if (s_red[i] > bb) { bb = s_red[i]; jj = s_redj[i]; }
        s_win[r] = s_cidx[jj];
        s_sims[jj] = -1e300;
      }
      __syncthreads();
    }
  }

  // gather 8 winner rows, mean, write fp32 output
  float ax = 0.f, ay = 0.f;
#pragma unroll
  for (int r = 0; r < TOPK; r++) {
    const float2 v = *(const float2*)(mem + (size_t)s_win[r] * DIM + tid * 2);
    ax += v.x; ay += v.y;
  }
  float2 o; o.x = ax * 0.125f; o.y = ay * 0.125f;
  *(float2*)(out + (size_t)b * DIM + tid * 2) = o;
}

extern "C" void kernel_launch(void* const* d_in, const int* in_sizes, int n_in,
                              void* d_out, int out_size, void* d_ws, size_t ws_size,
                              hipStream_t stream) {
  (void)in_sizes; (void)n_in; (void)out_size; (void)ws_size;
  const float* q = (const float*)d_in[0];
  const float* mem = (const float*)d_in[1];
  float* out = (float*)d_out;

  char* ws = (char*)d_ws;
  s8* mn8 = (s8*)ws;                                          // 32 MB
  s8* qn8 = (s8*)(ws + (size_t)M_ROWS * DIM);                 // 2 MB
  float* sb = (float*)(ws + (size_t)(M_ROWS + B_ROWS) * DIM);          // 256 KB
  float* sa = (float*)((char*)sb + (size_t)M_ROWS * sizeof(float));    // 16 KB
  int* count = (int*)((char*)sa + (size_t)B_ROWS * sizeof(float));     // 16 KB
  u32* cand = (u32*)((char*)count + (size_t)B_ROWS * sizeof(int));     // 8 MB

  hipMemsetAsync(count, 0, B_ROWS * sizeof(int), stream);
  quant_kernel<<<(M_ROWS + B_ROWS) / 4, 256, 0, stream>>>(mem, q, mn8, qn8, sb, sa);
  gemm_select<<<(B_ROWS / 128) * (M_ROWS / 128), 256, 0, stream>>>(qn8, mn8, sa, sb, count, cand);
  topk_kernel<<<B_ROWS, 256, 0, stream>>>(q, mem, count, cand, out);
}

// Round 17
// 305.701 us; speedup vs baseline: 1.7906x; 1.7906x over previous
//
#include <hip/hip_runtime.h>
#include <hip/hip_bf16.h>

#define B_ROWS 4096
#define M_ROWS 65536
#define DIM 512
#define TOPK 8
#define CAP 512
#define NR 16               // rescored candidates (top-NR by approx sim)
#define TAU 0.132583f       // 3/sqrt(512): ~88 candidates/query expected
#define FB_N 2048           // fallback merge entries = 256 threads * 8

typedef unsigned short u16;
typedef unsigned int u32;
typedef signed char s8;
typedef unsigned char u8;
typedef int i32x4 __attribute__((ext_vector_type(4)));

__device__ inline void gl_lds16(const void* g, void* l) {
  __builtin_amdgcn_global_load_lds(
      (const __attribute__((address_space(1))) u32*)g,
      (__attribute__((address_space(3))) u32*)l, 16, 0, 0);
}

// ---- normalize rows -> per-row-scaled int8 (one wave per row; fused q+mem) ----
__global__ __launch_bounds__(256) void quant_kernel(const float* __restrict__ mem,
                                                    const float* __restrict__ q,
                                                    s8* __restrict__ mn8,
                                                    s8* __restrict__ qn8,
                                                    float* __restrict__ sb,
                                                    float* __restrict__ sa) {
  int gw = (int)((blockIdx.x * 256 + threadIdx.x) >> 6);
  int lane = threadIdx.x & 63;
  const float* in;
  s8* out;
  float* scale;
  int row;
  if (gw < M_ROWS) {
    in = mem; out = mn8; scale = sb; row = gw;
  } else {
    in = q; out = qn8; scale = sa; row = gw - M_ROWS;
  }
  const float4* r = (const float4*)(in + (size_t)row * DIM);
  float4 v0 = r[lane * 2 + 0];
  float4 v1 = r[lane * 2 + 1];
  float ss = v0.x*v0.x + v0.y*v0.y + v0.z*v0.z + v0.w*v0.w
           + v1.x*v1.x + v1.y*v1.y + v1.z*v1.z + v1.w*v1.w;
#pragma unroll
  for (int off = 32; off > 0; off >>= 1) ss += __shfl_xor(ss, off);
  float inv = 1.0f / fmaxf(sqrtf(ss), 1e-8f);
  float x[8] = {v0.x*inv, v0.y*inv, v0.z*inv, v0.w*inv,
                v1.x*inv, v1.y*inv, v1.z*inv, v1.w*inv};
  float ma = 0.f;
#pragma unroll
  for (int e = 0; e < 8; e++) ma = fmaxf(ma, fabsf(x[e]));
#pragma unroll
  for (int off = 32; off > 0; off >>= 1) ma = fmaxf(ma, __shfl_xor(ma, off));
  float s = fmaxf(ma, 1e-20f) * (1.0f / 127.0f);
  float rs = 1.0f / s;
  u32 lo = 0, hi = 0;
#pragma unroll
  for (int e = 0; e < 4; e++) {
    int qi = __float2int_rn(fminf(fmaxf(x[e] * rs, -127.f), 127.f));
    lo |= ((u32)(u8)(s8)qi) << (8 * e);
  }
#pragma unroll
  for (int e = 0; e < 4; e++) {
    int qi = __float2int_rn(fminf(fmaxf(x[4 + e] * rs, -127.f), 127.f));
    hi |= ((u32)(u8)(s8)qi) << (8 * e);
  }
  uint2 pk; pk.x = lo; pk.y = hi;
  *(uint2*)(out + (size_t)row * DIM + lane * 8) = pk;
  if (lane == 0) scale[row] = s;
}

// ---- int8 MFMA GEMM: 128x128 tile, BK=64 (8 K-steps FULLY UNROLLED ->
//      static slots + immediate-offset addressing), 4 waves, ring-2 LDS
//      (32KB) + launch_bounds(256,4) -> 4 blocks/CU. Super-row XOR swizzle
//      (0 conflicts), gl_lds width-16, setprio.
//      Epilogue: v = idot*sa*sb, packed (bf16sim<<16|idx) candidates. ----
__global__ __launch_bounds__(256, 4) void gemm_select(const s8* __restrict__ qn,
                                                      const s8* __restrict__ mn,
                                                      const float* __restrict__ sa,
                                                      const float* __restrict__ sb,
                                                      int* __restrict__ count,
                                                      u32* __restrict__ cand) {
  // ring of 2 K-step buffers: A[128 rows][64 B] = 8KB, B same -> 32 KiB
  __shared__ s8 sA[2][8192];
  __shared__ s8 sB[2][8192];

  // R8-proven mapping: XCD-pair owns a qband of 8 qtiles; 8 consecutive
  // same-XCD blocks share an mtile (8x L2 reuse of mn).
  int bid0 = blockIdx.x;
  int b1 = (bid0 & 7) * 2048 + (bid0 >> 3);
  int qtile = (b1 >> 12) * 8 + (b1 & 7);      // 0..31
  int mtile = (b1 >> 3) & 511;                // 0..511

  int tid = threadIdx.x;
  int lane = tid & 63;
  int w = tid >> 6;
  int wr = w >> 1, wc = w & 1;                // 2 x 2 wave grid; wave tile 64x64
  int rlo = lane & 15;
  int khi16 = (lane >> 4) << 4;               // byte offset of lane's 16B k-slice

  const s8* gA = qn + (size_t)qtile * 128 * DIM;
  const s8* gB = mn + (size_t)mtile * 128 * DIM;

  // staging: per issue 4KB (256 thr x 16B), dest byte = tid*16 (linear).
  // super-row (128B = 2 rows of 64B) XOR swizzle; source pre-swizzled
  // (inverse permutation) so swizzled READ returns logical data (rule #21).
  int brow_lo = tid >> 3;                     // super-row 0..31 per 4KB issue
  int innb = (tid & 7) << 4;                  // dest inner bytes 0..112
  int inns = innb ^ ((brow_lo & 7) << 4);     // logical inner for this dest slot
  int grow0 = brow_lo * 2 + (inns >> 6);      // logical row 0..63 (issue 0)
  int gcolb = inns & 63;                      // byte col within 64B row

  // precomputed per-lane bases (loop-invariant; kt*64 folds to immediates)
  const s8* gA0 = gA + (size_t)grow0 * DIM + gcolb;
  const s8* gA1 = gA + (size_t)(grow0 + 64) * DIM + gcolb;
  const s8* gB0 = gB + (size_t)grow0 * DIM + gcolb;
  const s8* gB1 = gB + (size_t)(grow0 + 64) * DIM + gcolb;
  s8* lA0 = &sA[0][w * 1024];
  s8* lA1 = &sA[0][4096 + w * 1024];
  s8* lB0 = &sB[0][w * 1024];
  s8* lB1 = &sB[0][4096 + w * 1024];

  auto stage = [&](int slot, int kt) {
    int so = slot * 8192;
    gl_lds16(gA0 + kt * 64, lA0 + so);
    gl_lds16(gA1 + kt * 64, lA1 + so);
    gl_lds16(gB0 + kt * 64, lB0 + so);
    gl_lds16(gB1 + kt * 64, lB1 + so);
  };

  // fragment read bases (loop-invariant phys offsets; slot adds 8192)
  auto physof = [&](int row) {
    int brow = row >> 1;
    return (brow << 7) + ((((row & 1) << 6) + khi16) ^ ((brow & 7) << 4));
  };
  const char* rbA = (const char*)&sA[0][0];
  const char* rbB = (const char*)&sB[0][0];
  int offA[4], offB[4];
#pragma unroll
  for (int i = 0; i < 4; i++) {
    offA[i] = physof(wr * 64 + i * 16 + rlo);
    offB[i] = physof(wc * 64 + i * 16 + rlo);
  }

  i32x4 acc[4][4];
#pragma unroll
  for (int i = 0; i < 4; i++)
#pragma unroll
    for (int jj = 0; jj < 4; jj++) {
      i32x4 z = {0, 0, 0, 0};
      acc[i][jj] = z;
    }

  // prologue: stage K-step 0 into slot 0 (4 vmem/thread in flight)
  stage(0, 0);

#pragma unroll
  for (int t = 0; t < 8; t++) {
    // only this slot's 4 loads in flight (issued a full step earlier)
    asm volatile("s_waitcnt vmcnt(0)" ::: "memory");
    __builtin_amdgcn_s_barrier();
    const int cs = t & 1;
    if (t < 7) stage(cs ^ 1, t + 1);  // overwrites slot read at t-1: readers
                                      // retired before this barrier
    i32x4 aF[4], bF[4];
#pragma unroll
    for (int mi = 0; mi < 4; mi++) aF[mi] = *(const i32x4*)(rbA + cs * 8192 + offA[mi]);
#pragma unroll
    for (int ni = 0; ni < 4; ni++) bF[ni] = *(const i32x4*)(rbB + cs * 8192 + offB[ni]);
    __builtin_amdgcn_s_setprio(1);
#pragma unroll
    for (int mi = 0; mi < 4; mi++)
#pragma unroll
      for (int ni = 0; ni < 4; ni++)
        acc[mi][ni] = __builtin_amdgcn_mfma_i32_16x16x64_i8(aF[mi], bF[ni], acc[mi][ni], 0, 0, 0);
    __builtin_amdgcn_s_setprio(0);
  }

  // epilogue: C row (query) = (lane>>4)*4 + reg, col (mem) = lane&15
  // (C/D layout is dtype-independent on gfx950). v = idot * sa * sb.
  int qbase = qtile * 128 + wr * 64 + (lane >> 4) * 4;
  int mbase = mtile * 128 + wc * 64 + (lane & 15);
#pragma unroll
  for (int mi = 0; mi < 4; mi++) {
    float4 sav = *(const float4*)&sa[qbase + mi * 16];
#pragma unroll
    for (int ni = 0; ni < 4; ni++) {
      float sbv = sb[mbase + ni * 16];
#pragma unroll
      for (int r = 0; r < 4; r++) {
        float v = (float)acc[mi][ni][r] * (sav[r] * sbv);
        if (v > TAU) {
          int qq = qbase + mi * 16 + r;
          u32 pk = (__builtin_bit_cast(u32, v) & 0xFFFF0000u) | (u32)(mbase + ni * 16);
          int pos = atomicAdd(&count[qq], 1);
          if (pos < CAP) cand[(size_t)qq * CAP + pos] = pk;
        }
      }
    }
  }
}

// ---- per-query: top-NR by packed approx sim, fp64 rescore of those rows,
//      exact top-8, gather+mean ----
__global__ __launch_bounds__(256) void topk_kernel(const float* __restrict__ q,
                                                   const float* __restrict__ mem,
                                                   const int* __restrict__ count,
                                                   const u32* __restrict__ cand,
                                                   float* __restrict__ out) {
  __shared__ double s_sims[FB_N];   // fallback merge buffer
  __shared__ int s_cidx[FB_N];
  __shared__ double s_red[4];
  __shared__ int s_redj[4];
  __shared__ u32 s_pk[CAP];
  __shared__ int s_sel[NR];
  __shared__ double s_x[NR];
  __shared__ int s_win[TOPK];

  int b = blockIdx.x;
  int tid = threadIdx.x;
  int lane = tid & 63;
  int w = tid >> 6;

  const float* qrow = q + (size_t)b * DIM;
  const float4* qv = (const float4*)qrow;
  float4 q0 = qv[lane * 2], q1 = qv[lane * 2 + 1];
  double q8[8] = {q0.x, q0.y, q0.z, q0.w, q1.x, q1.y, q1.z, q1.w};
  double qq = 0;
#pragma unroll
  for (int e = 0; e < 8; e++) qq += q8[e] * q8[e];
#pragma unroll
  for (int off = 32; off > 0; off >>= 1) qq += __shfl_xor(qq, off);
  double qnorm = fmax(sqrt(qq), 1e-8);

  int c = count[b];
  if (c >= TOPK && c <= CAP) {
    for (int j = tid; j < c; j += 256) s_pk[j] = cand[(size_t)b * CAP + j];
    __syncthreads();
    int nsel = c < NR ? c : NR;
    if (w == 0) {
      for (int r = 0; r < nsel; r++) {
        int best = -1, bj = -1;
        for (int j = lane; j < c; j += 64) {
          int v = (int)s_pk[j];
          if (v > best) { best = v; bj = j; }
        }
#pragma unroll
        for (int off = 32; off > 0; off >>= 1) {
          int ov = __shfl_down(best, off);
          int oj = __shfl_down(bj, off);
          if (ov > best) { best = ov; bj = oj; }
        }
        bj = __shfl(bj, 0);
        if (lane == 0) { s_sel[r] = (int)(s_pk[bj] & 0xFFFFu); s_pk[bj] = 0; }
      }
    }
    __syncthreads();
    for (int i = w; i < nsel; i += 4) {
      int mi = s_sel[i];
      const float4* mv = (const float4*)(mem + (size_t)mi * DIM);
      float4 m0 = mv[lane * 2], m1 = mv[lane * 2 + 1];
      double m8[8] = {m0.x, m0.y, m0.z, m0.w, m1.x, m1.y, m1.z, m1.w};
      double dot = 0, mm = 0;
#pragma unroll
      for (int e = 0; e < 8; e++) { dot += q8[e] * m8[e]; mm += m8[e] * m8[e]; }
#pragma unroll
      for (int off = 32; off > 0; off >>= 1) {
        dot += __shfl_xor(dot, off);
        mm += __shfl_xor(mm, off);
      }
      if (lane == 0) s_x[i] = dot / (qnorm * fmax(sqrt(mm), 1e-8));
    }
    __syncthreads();
    if (w == 0) {
      double myv = (lane < nsel) ? s_x[lane] : -1e300;
      int myrow = (lane < nsel) ? s_sel[lane] : -1;
      for (int r = 0; r < TOPK; r++) {
        double bv = myv; int bl = lane;
#pragma unroll
        for (int off = 32; off > 0; off >>= 1) {
          double ov = __shfl_down(bv, off);
          int ol = __shfl_down(bl, off);
          if (ov > bv) { bv = ov; bl = ol; }
        }
        bl = __shfl(bl, 0);
        int brow = __shfl(myrow, bl);
        if (lane == 0) s_win[r] = brow;
        if (lane == bl) myv = -1e300;
      }
    }
    __syncthreads();
  } else {
    // fallback (cold, correctness-only): full scan, per-thread top-8, block merge
    double tv[8]; int tix[8];
#pragma unroll
    for (int r = 0; r < 8; r++) { tv[r] = -1e300; tix[r] = -1; }
    for (int row = tid; row < M_ROWS; row += 256) {
      const float4* mv = (const float4*)(mem + (size_t)row * DIM);
      double dot = 0, mm = 0;
      for (int e = 0; e < DIM / 4; e++) {
        float4 m4 = mv[e], qk = qv[e];
        dot += (double)m4.x * qk.x + (double)m4.y * qk.y + (double)m4.z * qk.z + (double)m4.w * qk.w;
        mm  += (double)m4.x * m4.x + (double)m4.y * m4.y + (double)m4.z * m4.z + (double)m4.w * m4.w;
      }
      double sim = dot / (qnorm * fmax(sqrt(mm), 1e-8));
      int am = 0;
#pragma unroll
      for (int r = 1; r < 8; r++) if (tv[r] < tv[am]) am = r;
      if (sim > tv[am]) { tv[am] = sim; tix[am] = row; }
    }
#pragma unroll
    for (int r = 0; r < 8; r++) { s_sims[tid * 8 + r] = tv[r]; s_cidx[tid * 8 + r] = tix[r]; }
    __syncthreads();
    for (int r = 0; r < TOPK; r++) {
      double best = -1e300; int bj = -1;
      for (int j = tid; j < FB_N; j += 256) {
        double v = s_sims[j];
        if (v > best) { best = v; bj = j; }
      }
#pragma unroll
      for (int off = 32; off > 0; off >>= 1) {
        double ov = __shfl_down(best, off);
        int oj = __shfl_down(bj, off);
        if (ov > best) { best = ov; bj = oj; }
      }
      if (lane == 0) { s_red[w] = best; s_redj[w] = bj; }
      __syncthreads();
      if (tid == 0) {
        double bb = s_red[0]; int jj = s_redj[0];
        for (int i = 1; i < 4; i++) if (s_red[i] > bb) { bb = s_red[i]; jj = s_redj[i]; }
        s_win[r] = s_cidx[jj];
        s_sims[jj] = -1e300;
      }
      __syncthreads();
    }
  }

  // gather 8 winner rows, mean, write fp32 output
  float ax = 0.f, ay = 0.f;
#pragma unroll
  for (int r = 0; r < TOPK; r++) {
    const float2 v = *(const float2*)(mem + (size_t)s_win[r] * DIM + tid * 2);
    ax += v.x; ay += v.y;
  }
  float2 o; o.x = ax * 0.125f; o.y = ay * 0.125f;
  *(float2*)(out + (size_t)b * DIM + tid * 2) = o;
}

extern "C" void kernel_launch(void* const* d_in, const int* in_sizes, int n_in,
                              void* d_out, int out_size, void* d_ws, size_t ws_size,
                              hipStream_t stream) {
  (void)in_sizes; (void)n_in; (void)out_size; (void)ws_size;
  const float* q = (const float*)d_in[0];
  const float* mem = (const float*)d_in[1];
  float* out = (float*)d_out;

  char* ws = (char*)d_ws;
  s8* mn8 = (s8*)ws;                                          // 32 MB
  s8* qn8 = (s8*)(ws + (size_t)M_ROWS * DIM);                 // 2 MB
  float* sb = (float*)(ws + (size_t)(M_ROWS + B_ROWS) * DIM);          // 256 KB
  float* sa = (float*)((char*)sb + (size_t)M_ROWS * sizeof(float));    // 16 KB
  int* count = (int*)((char*)sa + (size_t)B_ROWS * sizeof(float));     // 16 KB
  u32* cand = (u32*)((char*)count + (size_t)B_ROWS * sizeof(int));     // 8 MB

  hipMemsetAsync(count, 0, B_ROWS * sizeof(int), stream);
  quant_kernel<<<(M_ROWS + B_ROWS) / 4, 256, 0, stream>>>(mem, q, mn8, qn8, sb, sa);
  gemm_select<<<(B_ROWS / 128) * (M_ROWS / 128), 256, 0, stream>>>(qn8, mn8, sa, sb, count, cand);
  topk_kernel<<<B_ROWS, 256, 0, stream>>>(q, mem, count, cand, out);
}

// Round 18
// 304.604 us; speedup vs baseline: 1.7970x; 1.0036x over previous
//
#include <hip/hip_runtime.h>
#include <hip/hip_bf16.h>

#define B_ROWS 4096
#define M_ROWS 65536
#define DIM 512
#define TOPK 8
#define CAP 512
#define NR 16               // rescored candidates (top-NR by approx sim)
#define TAU 0.132583f       // 3/sqrt(512): ~88 candidates/query expected
#define FB_N 2048           // fallback merge entries = 256 threads * 8

typedef unsigned short u16;
typedef unsigned int u32;
typedef signed char s8;
typedef unsigned char u8;
typedef int i32x4 __attribute__((ext_vector_type(4)));

__device__ inline void gl_lds16(const void* g, void* l) {
  __builtin_amdgcn_global_load_lds(
      (const __attribute__((address_space(1))) u32*)g,
      (__attribute__((address_space(3))) u32*)l, 16, 0, 0);
}

// ---- normalize rows -> per-row-scaled int8 (one wave per row; fused q+mem)
//      block 0 additionally zeroes count[] (stream-ordered before gemm) ----
__global__ __launch_bounds__(256) void quant_kernel(const float* __restrict__ mem,
                                                    const float* __restrict__ q,
                                                    s8* __restrict__ mn8,
                                                    s8* __restrict__ qn8,
                                                    float* __restrict__ sb,
                                                    float* __restrict__ sa,
                                                    int* __restrict__ count) {
  if (blockIdx.x == 0) {
    for (int i = threadIdx.x; i < B_ROWS; i += 256) count[i] = 0;
  }
  int gw = (int)((blockIdx.x * 256 + threadIdx.x) >> 6);
  int lane = threadIdx.x & 63;
  const float* in;
  s8* out;
  float* scale;
  int row;
  if (gw < M_ROWS) {
    in = mem; out = mn8; scale = sb; row = gw;
  } else {
    in = q; out = qn8; scale = sa; row = gw - M_ROWS;
  }
  const float4* r = (const float4*)(in + (size_t)row * DIM);
  float4 v0 = r[lane * 2 + 0];
  float4 v1 = r[lane * 2 + 1];
  float ss = v0.x*v0.x + v0.y*v0.y + v0.z*v0.z + v0.w*v0.w
           + v1.x*v1.x + v1.y*v1.y + v1.z*v1.z + v1.w*v1.w;
#pragma unroll
  for (int off = 32; off > 0; off >>= 1) ss += __shfl_xor(ss, off);
  float inv = 1.0f / fmaxf(sqrtf(ss), 1e-8f);
  float x[8] = {v0.x*inv, v0.y*inv, v0.z*inv, v0.w*inv,
                v1.x*inv, v1.y*inv, v1.z*inv, v1.w*inv};
  float ma = 0.f;
#pragma unroll
  for (int e = 0; e < 8; e++) ma = fmaxf(ma, fabsf(x[e]));
#pragma unroll
  for (int off = 32; off > 0; off >>= 1) ma = fmaxf(ma, __shfl_xor(ma, off));
  float s = fmaxf(ma, 1e-20f) * (1.0f / 127.0f);
  float rs = 1.0f / s;
  u32 lo = 0, hi = 0;
#pragma unroll
  for (int e = 0; e < 4; e++) {
    int qi = __float2int_rn(fminf(fmaxf(x[e] * rs, -127.f), 127.f));
    lo |= ((u32)(u8)(s8)qi) << (8 * e);
  }
#pragma unroll
  for (int e = 0; e < 4; e++) {
    int qi = __float2int_rn(fminf(fmaxf(x[4 + e] * rs, -127.f), 127.f));
    hi |= ((u32)(u8)(s8)qi) << (8 * e);
  }
  uint2 pk; pk.x = lo; pk.y = hi;
  *(uint2*)(out + (size_t)row * DIM + lane * 8) = pk;
  if (lane == 0) scale[row] = s;
}

// ---- int8 MFMA GEMM: 128x128 tile, BK=64 (8 K-steps FULLY UNROLLED ->
//      static slots + immediate-offset addressing), 4 waves, ring-2 LDS
//      (32KB) + launch_bounds(256,4) -> 4 blocks/CU. Super-row XOR swizzle
//      (0 conflicts), gl_lds width-16, setprio.
//      Epilogue: v = idot*sa*sb, packed (bf16sim<<16|idx) candidates. ----
__global__ __launch_bounds__(256, 4) void gemm_select(const s8* __restrict__ qn,
                                                      const s8* __restrict__ mn,
                                                      const float* __restrict__ sa,
                                                      const float* __restrict__ sb,
                                                      int* __restrict__ count,
                                                      u32* __restrict__ cand) {
  // ring of 2 K-step buffers: A[128 rows][64 B] = 8KB, B same -> 32 KiB
  __shared__ s8 sA[2][8192];
  __shared__ s8 sB[2][8192];

  // R8-proven mapping: XCD-pair owns a qband of 8 qtiles; 8 consecutive
  // same-XCD blocks share an mtile (8x L2 reuse of mn).
  int bid0 = blockIdx.x;
  int b1 = (bid0 & 7) * 2048 + (bid0 >> 3);
  int qtile = (b1 >> 12) * 8 + (b1 & 7);      // 0..31
  int mtile = (b1 >> 3) & 511;                // 0..511

  int tid = threadIdx.x;
  int lane = tid & 63;
  int w = tid >> 6;
  int wr = w >> 1, wc = w & 1;                // 2 x 2 wave grid; wave tile 64x64
  int rlo = lane & 15;
  int khi16 = (lane >> 4) << 4;               // byte offset of lane's 16B k-slice

  const s8* gA = qn + (size_t)qtile * 128 * DIM;
  const s8* gB = mn + (size_t)mtile * 128 * DIM;

  // staging: per issue 4KB (256 thr x 16B), dest byte = tid*16 (linear).
  // super-row (128B = 2 rows of 64B) XOR swizzle; source pre-swizzled
  // (inverse permutation) so swizzled READ returns logical data (rule #21).
  int brow_lo = tid >> 3;                     // super-row 0..31 per 4KB issue
  int innb = (tid & 7) << 4;                  // dest inner bytes 0..112
  int inns = innb ^ ((brow_lo & 7) << 4);     // logical inner for this dest slot
  int grow0 = brow_lo * 2 + (inns >> 6);      // logical row 0..63 (issue 0)
  int gcolb = inns & 63;                      // byte col within 64B row

  // precomputed per-lane bases (loop-invariant; kt*64 folds to immediates)
  const s8* gA0 = gA + (size_t)grow0 * DIM + gcolb;
  const s8* gA1 = gA + (size_t)(grow0 + 64) * DIM + gcolb;
  const s8* gB0 = gB + (size_t)grow0 * DIM + gcolb;
  const s8* gB1 = gB + (size_t)(grow0 + 64) * DIM + gcolb;
  s8* lA0 = &sA[0][w * 1024];
  s8* lA1 = &sA[0][4096 + w * 1024];
  s8* lB0 = &sB[0][w * 1024];
  s8* lB1 = &sB[0][4096 + w * 1024];

  auto stage = [&](int slot, int kt) {
    int so = slot * 8192;
    gl_lds16(gA0 + kt * 64, lA0 + so);
    gl_lds16(gA1 + kt * 64, lA1 + so);
    gl_lds16(gB0 + kt * 64, lB0 + so);
    gl_lds16(gB1 + kt * 64, lB1 + so);
  };

  // fragment read bases (loop-invariant phys offsets; slot adds 8192)
  auto physof = [&](int row) {
    int brow = row >> 1;
    return (brow << 7) + ((((row & 1) << 6) + khi16) ^ ((brow & 7) << 4));
  };
  const char* rbA = (const char*)&sA[0][0];
  const char* rbB = (const char*)&sB[0][0];
  int offA[4], offB[4];
#pragma unroll
  for (int i = 0; i < 4; i++) {
    offA[i] = physof(wr * 64 + i * 16 + rlo);
    offB[i] = physof(wc * 64 + i * 16 + rlo);
  }

  i32x4 acc[4][4];
#pragma unroll
  for (int i = 0; i < 4; i++)
#pragma unroll
    for (int jj = 0; jj < 4; jj++) {
      i32x4 z = {0, 0, 0, 0};
      acc[i][jj] = z;
    }

  // prologue: stage K-step 0 into slot 0 (4 vmem/thread in flight)
  stage(0, 0);

#pragma unroll
  for (int t = 0; t < 8; t++) {
    // only this slot's 4 loads in flight (issued a full step earlier)
    asm volatile("s_waitcnt vmcnt(0)" ::: "memory");
    __builtin_amdgcn_s_barrier();
    const int cs = t & 1;
    if (t < 7) stage(cs ^ 1, t + 1);  // overwrites slot read at t-1: readers
                                      // retired before this barrier
    i32x4 aF[4], bF[4];
#pragma unroll
    for (int mi = 0; mi < 4; mi++) aF[mi] = *(const i32x4*)(rbA + cs * 8192 + offA[mi]);
#pragma unroll
    for (int ni = 0; ni < 4; ni++) bF[ni] = *(const i32x4*)(rbB + cs * 8192 + offB[ni]);
    __builtin_amdgcn_s_setprio(1);
#pragma unroll
    for (int mi = 0; mi < 4; mi++)
#pragma unroll
      for (int ni = 0; ni < 4; ni++)
        acc[mi][ni] = __builtin_amdgcn_mfma_i32_16x16x64_i8(aF[mi], bF[ni], acc[mi][ni], 0, 0, 0);
    __builtin_amdgcn_s_setprio(0);
  }

  // epilogue: C row (query) = (lane>>4)*4 + reg, col (mem) = lane&15
  // (C/D layout is dtype-independent on gfx950). v = idot * sa * sb.
  int qbase = qtile * 128 + wr * 64 + (lane >> 4) * 4;
  int mbase = mtile * 128 + wc * 64 + (lane & 15);
#pragma unroll
  for (int mi = 0; mi < 4; mi++) {
    float4 sav = *(const float4*)&sa[qbase + mi * 16];
#pragma unroll
    for (int ni = 0; ni < 4; ni++) {
      float sbv = sb[mbase + ni * 16];
#pragma unroll
      for (int r = 0; r < 4; r++) {
        float v = (float)acc[mi][ni][r] * (sav[r] * sbv);
        if (v > TAU) {
          int qq = qbase + mi * 16 + r;
          u32 pk = (__builtin_bit_cast(u32, v) & 0xFFFF0000u) | (u32)(mbase + ni * 16);
          int pos = atomicAdd(&count[qq], 1);
          if (pos < CAP) cand[(size_t)qq * CAP + pos] = pk;
        }
      }
    }
  }
}

// ---- per-query: top-NR by packed approx sim, fp64 rescore of those rows
//      (rows cached in LDS), exact top-8, gather from LDS cache + mean.
//      Row cache (32KB) is UNIONED with the fallback merge buffers. ----
__global__ __launch_bounds__(256) void topk_kernel(const float* __restrict__ q,
                                                   const float* __restrict__ mem,
                                                   const int* __restrict__ count,
                                                   const u32* __restrict__ cand,
                                                   float* __restrict__ out) {
  __shared__ char s_buf[32768];     // normal: float rows[NR][512]; fallback:
                                    // double sims[2048] (16K) + int cidx[2048] (8K)
  __shared__ double s_red[4];
  __shared__ int s_redj[4];
  __shared__ u32 s_pk[CAP];
  __shared__ int s_sel[NR];
  __shared__ double s_x[NR];
  __shared__ int s_win[TOPK];
  __shared__ int s_winslot[TOPK];

  int b = blockIdx.x;
  int tid = threadIdx.x;
  int lane = tid & 63;
  int w = tid >> 6;

  const float* qrow = q + (size_t)b * DIM;
  const float4* qv = (const float4*)qrow;
  float4 q0 = qv[lane * 2], q1 = qv[lane * 2 + 1];
  double q8[8] = {q0.x, q0.y, q0.z, q0.w, q1.x, q1.y, q1.z, q1.w};
  double qq = 0;
#pragma unroll
  for (int e = 0; e < 8; e++) qq += q8[e] * q8[e];
#pragma unroll
  for (int off = 32; off > 0; off >>= 1) qq += __shfl_xor(qq, off);
  double qnorm = fmax(sqrt(qq), 1e-8);

  int c = count[b];
  if (c >= TOPK && c <= CAP) {
    float* s_rows = (float*)s_buf;  // [NR][512]
    for (int j = tid; j < c; j += 256) s_pk[j] = cand[(size_t)b * CAP + j];
    __syncthreads();
    int nsel = c < NR ? c : NR;
    if (w == 0) {
      for (int r = 0; r < nsel; r++) {
        int best = -1, bj = -1;
        for (int j = lane; j < c; j += 64) {
          int v = (int)s_pk[j];
          if (v > best) { best = v; bj = j; }
        }
#pragma unroll
        for (int off = 32; off > 0; off >>= 1) {
          int ov = __shfl_down(best, off);
          int oj = __shfl_down(bj, off);
          if (ov > best) { best = ov; bj = oj; }
        }
        bj = __shfl(bj, 0);
        if (lane == 0) { s_sel[r] = (int)(s_pk[bj] & 0xFFFFu); s_pk[bj] = 0; }
      }
    }
    __syncthreads();
    // fp64 rescore; also cache each row's fp32 data in LDS for the gather
    for (int i = w; i < nsel; i += 4) {
      int mi = s_sel[i];
      const float4* mv = (const float4*)(mem + (size_t)mi * DIM);
      float4 m0 = mv[lane * 2], m1 = mv[lane * 2 + 1];
      *(float4*)&s_rows[i * DIM + lane * 8] = m0;
      *(float4*)&s_rows[i * DIM + lane * 8 + 4] = m1;
      double m8[8] = {m0.x, m0.y, m0.z, m0.w, m1.x, m1.y, m1.z, m1.w};
      double dot = 0, mm = 0;
#pragma unroll
      for (int e = 0; e < 8; e++) { dot += q8[e] * m8[e]; mm += m8[e] * m8[e]; }
#pragma unroll
      for (int off = 32; off > 0; off >>= 1) {
        dot += __shfl_xor(dot, off);
        mm += __shfl_xor(mm, off);
      }
      if (lane == 0) s_x[i] = dot / (qnorm * fmax(sqrt(mm), 1e-8));
    }
    __syncthreads();
    if (w == 0) {
      double myv = (lane < nsel) ? s_x[lane] : -1e300;
      for (int r = 0; r < TOPK; r++) {
        double bv = myv; int bl = lane;
#pragma unroll
        for (int off = 32; off > 0; off >>= 1) {
          double ov = __shfl_down(bv, off);
          int ol = __shfl_down(bl, off);
          if (ov > bv) { bv = ov; bl = ol; }
        }
        bl = __shfl(bl, 0);
        if (lane == 0) s_winslot[r] = bl;   // slot in the row cache
        if (lane == bl) myv = -1e300;
      }
    }
    __syncthreads();
    // gather 8 winner rows FROM LDS CACHE, mean, write fp32 output
    float ax = 0.f, ay = 0.f;
#pragma unroll
    for (int r = 0; r < TOPK; r++) {
      const float2 v = *(const float2*)&s_rows[s_winslot[r] * DIM + tid * 2];
      ax += v.x; ay += v.y;
    }
    float2 o; o.x = ax * 0.125f; o.y = ay * 0.125f;
    *(float2*)(out + (size_t)b * DIM + tid * 2) = o;
  } else {
    // fallback (cold, correctness-only): full scan, per-thread top-8, block merge
    double* s_sims = (double*)s_buf;          // [FB_N] = 16KB
    int* s_cidx = (int*)(s_buf + 16384);      // [FB_N] = 8KB
    double tv[8]; int tix[8];
#pragma unroll
    for (int r = 0; r < 8; r++) { tv[r] = -1e300; tix[r] = -1; }
    for (int row = tid; row < M_ROWS; row += 256) {
      const float4* mv = (const float4*)(mem + (size_t)row * DIM);
      double dot = 0, mm = 0;
      for (int e = 0; e < DIM / 4; e++) {
        float4 m4 = mv[e], qk = qv[e];
        dot += (double)m4.x * qk.x + (double)m4.y * qk.y + (double)m4.z * qk.z + (double)m4.w * qk.w;
        mm  += (double)m4.x * m4.x + (double)m4.y * m4.y + (double)m4.z * m4.z + (double)m4.w * m4.w;
      }
      double sim = dot / (qnorm * fmax(sqrt(mm), 1e-8));
      int am = 0;
#pragma unroll
      for (int r = 1; r < 8; r++) if (tv[r] < tv[am]) am = r;
      if (sim > tv[am]) { tv[am] = sim; tix[am] = row; }
    }
#pragma unroll
    for (int r = 0; r < 8; r++) { s_sims[tid * 8 + r] = tv[r]; s_cidx[tid * 8 + r] = tix[r]; }
    __syncthreads();
    for (int r = 0; r < TOPK; r++) {
      double best = -1e300; int bj = -1;
      for (int j = tid; j < FB_N; j += 256) {
        double v = s_sims[j];
        if (v > best) { best = v; bj = j; }
      }
#pragma unroll
      for (int off = 32; off > 0; off >>= 1) {
        double ov = __shfl_down(best, off);
        int oj = __shfl_down(bj, off);
        if (ov > best) { best = ov; bj = oj; }
      }
      if (lane == 0) { s_red[w] = best; s_redj[w] = bj; }
      __syncthreads();
      if (tid == 0) {
        double bb = s_red[0]; int jj = s_redj[0];
        for (int i = 1; i < 4; i++) if (s_red[i] > bb) { bb = s_red[i]; jj = s_redj[i]; }
        s_win[r] = s_cidx[jj];
        s_sims[jj] = -1e300;
      }
      __syncthreads();
    }
    // gather 8 winner rows from global, mean, write fp32 output
    float ax = 0.f, ay = 0.f;
#pragma unroll
    for (int r = 0; r < TOPK; r++) {
      const float2 v = *(const float2*)(mem + (size_t)s_win[r] * DIM + tid * 2);
      ax += v.x; ay += v.y;
    }
    float2 o; o.x = ax * 0.125f; o.y = ay * 0.125f;
    *(float2*)(out + (size_t)b * DIM + tid * 2) = o;
  }
}

extern "C" void kernel_launch(void* const* d_in, const int* in_sizes, int n_in,
                              void* d_out, int out_size, void* d_ws, size_t ws_size,
                              hipStream_t stream) {
  (void)in_sizes; (void)n_in; (void)out_size; (void)ws_size;
  const float* q = (const float*)d_in[0];
  const float* mem = (const float*)d_in[1];
  float* out = (float*)d_out;

  char* ws = (char*)d_ws;
  s8* mn8 = (s8*)ws;                                          // 32 MB
  s8* qn8 = (s8*)(ws + (size_t)M_ROWS * DIM);                 // 2 MB
  float* sb = (float*)(ws + (size_t)(M_ROWS + B_ROWS) * DIM);          // 256 KB
  float* sa = (float*)((char*)sb + (size_t)M_ROWS * sizeof(float));    // 16 KB
  int* count = (int*)((char*)sa + (size_t)B_ROWS * sizeof(float));     // 16 KB
  u32* cand = (u32*)((char*)count + (size_t)B_ROWS * sizeof(int));     // 8 MB

  quant_kernel<<<(M_ROWS + B_ROWS) / 4, 256, 0, stream>>>(mem, q, mn8, qn8, sb, sa, count);
  gemm_select<<<(B_ROWS / 128) * (M_ROWS / 128), 256, 0, stream>>>(qn8, mn8, sa, sb, count, cand);
  topk_kernel<<<B_ROWS, 256, 0, stream>>>(q, mem, count, cand, out);
}